// Round 4
// baseline (6551.787 us; speedup 1.0000x reference)
//
#include <hip/hip_runtime.h>
#include <hip/hip_bf16.h>

typedef float   f32x4_t  __attribute__((ext_vector_type(4)));
typedef float   f32x2_t  __attribute__((ext_vector_type(2)));
typedef __bf16  bf16x8_t __attribute__((ext_vector_type(8)));
typedef int     i32x4_t  __attribute__((ext_vector_type(4)));

#define N_ROWS   16384
#define N_COLS   1000
#define N_COLS_P 1024
#define N_DIM    512
#define N_ITER   100
#define PBLK     256
#define PTHR     512
#define RED_BLOCKS 64     /* blocks 0..63 reduce 16 contiguous cols each */

__device__ __forceinline__ unsigned short f2bf(float f) {
    unsigned int u = __builtin_bit_cast(unsigned int, f);
    u += 0x7FFFu + ((u >> 16) & 1u);            // RNE round to bf16
    return (unsigned short)(u >> 16);
}

// Grid barrier: per-block arrival slots, leader block 0 polls with wave 0,
// release-stores generation. AGENT scope handles cross-XCD (guide §6 G16).
// Protocol validated in round 3 (results matched reference).
__device__ __forceinline__ void gridbar(int* bar, int g) {
    __syncthreads();
    if (blockIdx.x == 0) {
        if (threadIdx.x == 0)
            __hip_atomic_store(bar + 0, g, __ATOMIC_RELEASE, __HIP_MEMORY_SCOPE_AGENT);
        if (threadIdx.x < 64) {
            const int l = threadIdx.x;
            for (;;) {
                int ok = 1;
#pragma unroll
                for (int h = 0; h < 4; ++h)
                    ok &= (__hip_atomic_load(bar + (h << 6) + l, __ATOMIC_RELAXED,
                                             __HIP_MEMORY_SCOPE_AGENT) >= g);
                if (__all(ok)) break;
                __builtin_amdgcn_s_sleep(1);
            }
            __threadfence();
            if (l == 0)
                __hip_atomic_store(bar + 256, g, __ATOMIC_RELEASE, __HIP_MEMORY_SCOPE_AGENT);
        }
    } else {
        if (threadIdx.x == 0) {
            __hip_atomic_store(bar + blockIdx.x, g, __ATOMIC_RELEASE, __HIP_MEMORY_SCOPE_AGENT);
            while (__hip_atomic_load(bar + 256, __ATOMIC_ACQUIRE, __HIP_MEMORY_SCOPE_AGENT) < g)
                __builtin_amdgcn_s_sleep(2);
        }
    }
    __syncthreads();
}

// ---------------------------------------------------------------------------
// GEMM pass: dot = F @ T^T ; K = exp(-2*s/(1-s)), s=2*dot.
// MODE 0: K as bf16 (stride 1024, zero-padded) into d_out + column partials.
// MODE 1: final plan out[i][j] = u[i]*K[i][j]*v[j] (f32, stride 1000).
// ---------------------------------------------------------------------------
template <int MODE>
__launch_bounds__(256)
__global__ void k_gemm(const float* __restrict__ F, const float* __restrict__ T,
                       void* __restrict__ Kout, float* __restrict__ cpart,
                       const float* __restrict__ v_com, const float* __restrict__ u_both,
                       const int* __restrict__ flags)
{
    __shared__ unsigned short lA[128 * 72];
    __shared__ unsigned short lB[128 * 72];
    __shared__ float cs_lds[4 * 64];

    const int bm = blockIdx.x;
    const int bn = blockIdx.y;
    const int m0 = bm << 7;
    const int n0 = bn << 7;
    const int t  = threadIdx.x;
    const int lane = t & 63;
    const int wid  = t >> 6;
    const int wr = wid >> 1;
    const int wc = wid & 1;

    f32x4_t acc[4][4];
#pragma unroll
    for (int a = 0; a < 4; ++a)
#pragma unroll
        for (int b = 0; b < 4; ++b)
            acc[a][b] = (f32x4_t){0.f, 0.f, 0.f, 0.f};

    const int srow = t >> 4;
    const int scol = (t & 15) << 2;

    for (int kt = 0; kt < N_DIM; kt += 64) {
#pragma unroll
        for (int r = 0; r < 8; ++r) {
            const int rr = srow + (r << 4);
            const float4 av = *(const float4*)(F + (size_t)(m0 + rr) * N_DIM + kt + scol);
            ushort4 a4; a4.x = f2bf(av.x); a4.y = f2bf(av.y); a4.z = f2bf(av.z); a4.w = f2bf(av.w);
            *(ushort4*)(&lA[rr * 72 + scol]) = a4;
            const int gn = n0 + rr;
            float4 bv = make_float4(0.f, 0.f, 0.f, 0.f);
            if (gn < N_COLS) bv = *(const float4*)(T + (size_t)gn * N_DIM + kt + scol);
            ushort4 b4; b4.x = f2bf(bv.x); b4.y = f2bf(bv.y); b4.z = f2bf(bv.z); b4.w = f2bf(bv.w);
            *(ushort4*)(&lB[rr * 72 + scol]) = b4;
        }
        __syncthreads();
#pragma unroll
        for (int ks = 0; ks < 2; ++ks) {
            bf16x8_t afr[4], bfr[4];
#pragma unroll
            for (int mf = 0; mf < 4; ++mf) {
                const int r = (wr << 6) + (mf << 4) + (lane & 15);
                const int off = r * 72 + (ks << 5) + ((lane >> 4) << 3);
                afr[mf] = __builtin_bit_cast(bf16x8_t, *(const i32x4_t*)(&lA[off]));
            }
#pragma unroll
            for (int nf = 0; nf < 4; ++nf) {
                const int r = (wc << 6) + (nf << 4) + (lane & 15);
                const int off = r * 72 + (ks << 5) + ((lane >> 4) << 3);
                bfr[nf] = __builtin_bit_cast(bf16x8_t, *(const i32x4_t*)(&lB[off]));
            }
#pragma unroll
            for (int mf = 0; mf < 4; ++mf)
#pragma unroll
                for (int nf = 0; nf < 4; ++nf)
                    acc[mf][nf] = __builtin_amdgcn_mfma_f32_16x16x32_bf16(
                        afr[mf], bfr[nf], acc[mf][nf], 0, 0, 0);
        }
        __syncthreads();
    }

    int usel = 2;
    if (MODE == 1) usel = flags[1];
    float csum[4] = {0.f, 0.f, 0.f, 0.f};
#pragma unroll
    for (int mf = 0; mf < 4; ++mf) {
#pragma unroll
        for (int nf = 0; nf < 4; ++nf) {
#pragma unroll
            for (int j = 0; j < 4; ++j) {
                const float d = acc[mf][nf][j];
                const float s = 2.f * d;
                const float M = s / (1.f - s);
                const float kv = __expf(-2.f * M);
                const int grow = m0 + (wr << 6) + (mf << 4) + ((lane >> 4) << 2) + j;
                const int gcol = n0 + (wc << 6) + (nf << 4) + (lane & 15);
                if (MODE == 0) {
                    ((unsigned short*)Kout)[(size_t)grow * N_COLS_P + gcol] =
                        (gcol < N_COLS) ? f2bf(kv) : (unsigned short)0;
                    csum[nf] += kv;
                } else {
                    if (gcol < N_COLS) {
                        const float u = (usel == 2) ? (1.f / 16384.f)
                                                    : u_both[(size_t)usel * N_ROWS + grow];
                        ((float*)Kout)[(size_t)grow * N_COLS + gcol] = u * kv * v_com[gcol];
                    }
                }
            }
        }
    }
    if (MODE == 0) {
#pragma unroll
        for (int nf = 0; nf < 4; ++nf) {
            csum[nf] += __shfl_xor(csum[nf], 16);
            csum[nf] += __shfl_xor(csum[nf], 32);
        }
        if (lane < 16) {
#pragma unroll
            for (int nf = 0; nf < 4; ++nf)
                cs_lds[wid * 64 + (nf << 4) + lane] = csum[nf];
        }
        __syncthreads();
        if (t < 128) {
            const int cw = t >> 6;
            const int c6 = t & 63;
            cpart[(size_t)bm * N_COLS_P + n0 + t] =
                cs_lds[cw * 64 + c6] + cs_lds[(cw + 2) * 64 + c6];
        }
    }
}

// ---------------------------------------------------------------------------
// init: KtU0 = colsum(K)/16384, v_com = 1/1000, pads = 1.0, flags/bar reset.
// flags: [0]=unused [1]=u_sel (2=uniform u0) [2]=bad [3]=unused
// ---------------------------------------------------------------------------
__launch_bounds__(128)
__global__ void k_init(const float* __restrict__ cpart, float* __restrict__ ktu0,
                       float* __restrict__ vcom, float* __restrict__ err2,
                       int* __restrict__ flags, int* __restrict__ bar)
{
    const int j = blockIdx.x * 128 + threadIdx.x;   // 0..1023
    if (j < N_COLS) {
        float s = 0.f;
        for (int p = 0; p < 128; ++p) s += cpart[(size_t)p * N_COLS_P + j];
        ktu0[j] = s * (1.f / 16384.f);
        vcom[j] = 1.f / 1000.f;
    } else {
        ktu0[j] = 1.f;                 // pad: b=0 -> v=0 (finite)
        vcom[j] = 0.f;
    }
    if (j < 256) { err2[j] = 0.f; bar[j] = 0; }
    if (j == 257) bar[256] = 0;        // generation
    if (j == 0) { flags[0] = 0; flags[1] = 2; flags[2] = 0; flags[3] = 0; }
}

// ---------------------------------------------------------------------------
// Persistent Sinkhorn loop. 256 blocks x 512 thr (1 block/CU, co-resident).
// Lane owns column PAIRS {128q + 2*lane + e} (conflict-free LDS, coalesced
// preload); 8 rows per wave; packed bf16 K in 64 VGPRs.
// Per iter: A) vnew (LDS, 2 div/thread) -> dots -> u_new -> col partials
//              (one exclusive 4KB row per block);
//           B) 64 blocks reduce 16 contiguous cols each (float4 coalesced);
//           C) uniform done/converged decision.
// ---------------------------------------------------------------------------
__launch_bounds__(PTHR, 2)
__global__ void k_persist(const unsigned short* __restrict__ Kb,
                          const float* __restrict__ ratios,
                          float* __restrict__ ktu,      // [2][1024]
                          float* __restrict__ utmp,     // [2][16384]
                          float* __restrict__ vcom,     // [1024]
                          float* __restrict__ partials, // [256][1024]
                          float* __restrict__ err2,     // [256]
                          int* __restrict__ flags,
                          int* __restrict__ bar)        // [257]
{
    __shared__ float vnew[N_COLS_P];
    __shared__ float wp[8][N_COLS_P];
    __shared__ float wredf[4][16];
    __shared__ float errl[16];
    __shared__ float errw[4];
    __shared__ int ibc[2];
    const int t = threadIdx.x, lane = t & 63, wid = t >> 6, b = blockIdx.x;
    const int row0 = (b << 6) + (wid << 3);

    // K preload: packed bf16 pairs, fully coalesced dword loads.
    unsigned kp[8][8];
#pragma unroll
    for (int r = 0; r < 8; ++r) {
        const unsigned* rp = (const unsigned*)(Kb + (size_t)(row0 + r) * N_COLS_P);
#pragma unroll
        for (int q = 0; q < 8; ++q) kp[r][q] = rp[(q << 6) + lane];
    }
    // b for this thread's 2 vnew columns (constant across iters)
    const float bj0 = (t < N_COLS) ? ratios[t] * 16384.f : 0.f;
    const float bj1 = (t + PTHR < N_COLS) ? ratios[t + PTHR] * 16384.f : 0.f;

    int bar_g = 0;
    int usel = 2;

    for (int ii = 0; ii < N_ITER; ++ii) {
        const int p = ii & 1;
        const float* __restrict__ ktu_cur = ktu + p * N_COLS_P;
        float* __restrict__ ktu_nxt = ktu + (1 - p) * N_COLS_P;

        // ---- phase A ----
        int badl = 0;
        {
            const float v0 = bj0 / ktu_cur[t];
            const float v1 = bj1 / ktu_cur[t + PTHR];
            badl |= !isfinite(v0) | !isfinite(v1);
            vnew[t] = v0;
            vnew[t + PTHR] = v1;
        }
        __syncthreads();
        float vr[16];
#pragma unroll
        for (int q = 0; q < 8; ++q) {
            const f32x2_t vv = *(const f32x2_t*)&vnew[(q << 7) + (lane << 1)];
            vr[2*q] = vv[0]; vr[2*q+1] = vv[1];
        }
        float dots[8];
#pragma unroll
        for (int r = 0; r < 8; ++r) {
            float p0 = 0.f, p1 = 0.f, p2 = 0.f, p3 = 0.f;
#pragma unroll
            for (int q = 0; q < 8; ++q) {
                const unsigned u = kp[r][q];
                const float lo = __builtin_bit_cast(float, u << 16);
                const float hi = __builtin_bit_cast(float, u & 0xFFFF0000u);
                if (q & 1) { p2 = fmaf(lo, vr[2*q], p2); p3 = fmaf(hi, vr[2*q+1], p3); }
                else       { p0 = fmaf(lo, vr[2*q], p0); p1 = fmaf(hi, vr[2*q+1], p1); }
            }
            dots[r] = (p0 + p1) + (p2 + p3);
        }
#pragma unroll
        for (int s = 1; s <= 32; s <<= 1) {
#pragma unroll
            for (int r = 0; r < 8; ++r) dots[r] += __shfl_xor(dots[r], s);
        }
        float u8[8];
#pragma unroll
        for (int r = 0; r < 8; ++r) { u8[r] = 1.f / dots[r]; badl |= !isfinite(u8[r]); }
        if (lane == 0) {
            float* uo = utmp + (size_t)p * N_ROWS + row0;
#pragma unroll
            for (int r = 0; r < 8; ++r) uo[r] = u8[r];
        }
        if (__any(badl) && lane == 0) atomicOr(&flags[2], 1);

        float creg[16];
#pragma unroll
        for (int e = 0; e < 16; ++e) creg[e] = 0.f;
#pragma unroll
        for (int r = 0; r < 8; ++r) {
#pragma unroll
            for (int q = 0; q < 8; ++q) {
                const unsigned u = kp[r][q];
                const float lo = __builtin_bit_cast(float, u << 16);
                const float hi = __builtin_bit_cast(float, u & 0xFFFF0000u);
                creg[2*q]   = fmaf(lo, u8[r], creg[2*q]);
                creg[2*q+1] = fmaf(hi, u8[r], creg[2*q+1]);
            }
        }
#pragma unroll
        for (int q = 0; q < 8; ++q)
            *(f32x2_t*)&wp[wid][(q << 7) + (lane << 1)] = (f32x2_t){creg[2*q], creg[2*q+1]};
        __syncthreads();
        {
            const int j2 = t << 1;
            f32x2_t s2 = *(const f32x2_t*)&wp[0][j2];
#pragma unroll
            for (int w = 1; w < 8; ++w) {
                const f32x2_t x = *(const f32x2_t*)&wp[w][j2];
                s2[0] += x[0]; s2[1] += x[1];
            }
            *(f32x2_t*)&partials[(size_t)b * N_COLS_P + j2] = s2;
        }
        ++bar_g; gridbar(bar, bar_g);

        // ---- phase B: 64 blocks reduce 16 contiguous cols, coalesced ----
        if (t == 0) ibc[0] = __hip_atomic_load(&flags[2], __ATOMIC_RELAXED,
                                               __HIP_MEMORY_SCOPE_AGENT);
        __syncthreads();
        const int bad = ibc[0];
        if (!bad && b < RED_BLOCKS && t < 256) {
            const int w = t >> 6;                 // 0..3
            const int c0r = b << 4;               // 16 cols, 64B aligned
            f32x4_t part = (f32x4_t){0.f, 0.f, 0.f, 0.f};
#pragma unroll
            for (int k = 0; k < 4; ++k) {
                const int row = (w << 6) + (lane >> 2) + (k << 4);
                const f32x4_t x = *(const f32x4_t*)&partials[(size_t)row * N_COLS_P
                                                             + c0r + ((lane & 3) << 2)];
#pragma unroll
                for (int e = 0; e < 4; ++e) part[e] += x[e];
            }
#pragma unroll
            for (int sh = 4; sh <= 32; sh <<= 1) {
#pragma unroll
                for (int e = 0; e < 4; ++e) part[e] += __shfl_xor(part[e], sh);
            }
            if (lane < 4) *(f32x4_t*)&wredf[w][lane << 2] = part;
        }
        __syncthreads();
        if (!bad && b < RED_BLOCKS && t < 16) {
            const int col = (b << 4) + t;
            const float s = wredf[0][t] + wredf[1][t] + wredf[2][t] + wredf[3][t];
            float errc = 0.f;
            if (col < N_COLS) {
                ktu_nxt[col] = s;
                const float bj = ratios[col] * 16384.f;
                const float vn = bj / ktu_cur[col];
                const float d  = s * vn - bj;
                errc = d * d;
            } else {
                ktu_nxt[col] = 1.f;
            }
            errl[t] = errc;
        }
        __syncthreads();
        if (!bad && b < RED_BLOCKS && t == 0) {
            float e = 0.f;
#pragma unroll
            for (int i = 0; i < 16; ++i) e += errl[i];
            err2[b] = e;
        }
        ++bar_g; gridbar(bar, bar_g);

        // ---- phase C (uniform across blocks) ----
        if (bad) break;                  // revert: ktu/usel untouched this iter
        usel = p;                        // live commit
        if ((ii % 10) == 0) {
            float e = (t < 256) ? err2[t] : 0.f;
#pragma unroll
            for (int sh = 1; sh <= 32; sh <<= 1) e += __shfl_xor(e, sh);
            if (t < 256 && lane == 0) errw[wid] = e;
            __syncthreads();
            if (t == 0) ibc[1] = ((errw[0] + errw[1] + errw[2] + errw[3]) < 1e-18f) ? 1 : 0;
            __syncthreads();
            if (ibc[1]) break;           // converged (after committing this iter)
        }
    }

    if (b < RED_BLOCKS && t < 16 && usel != 2) {
        const int col = (b << 4) + t;
        if (col < N_COLS)
            vcom[col] = (ratios[col] * 16384.f) / ktu[(size_t)usel * N_COLS_P + col];
    }
    if (b == 0 && t == 0) flags[1] = usel;
}

extern "C" void kernel_launch(void* const* d_in, const int* in_sizes, int n_in,
                              void* d_out, int out_size, void* d_ws, size_t ws_size,
                              hipStream_t stream)
{
    const float* F      = (const float*)d_in[0];
    const float* T      = (const float*)d_in[1];
    const float* ratios = (const float*)d_in[2];
    float* out = (float*)d_out;
    unsigned short* Kb = (unsigned short*)d_out;   // bf16 K, stride 1024

    float* ws        = (float*)d_ws;
    float* partials  = ws;                                   // 256*1024
    float* ktu       = partials + (size_t)PBLK * N_COLS_P;   // 2*1024
    float* utmp      = ktu + 2 * N_COLS_P;                   // 2*16384
    float* vcom      = utmp + 2 * N_ROWS;                    // 1024
    float* err2      = vcom + N_COLS_P;                      // 256
    int*   flags     = (int*)(err2 + 256);                   // 4
    int*   bar       = flags + 4;                            // 257
    const size_t need_bytes = ((size_t)PBLK * N_COLS_P + 2 * N_COLS_P + 2 * N_ROWS +
                               N_COLS_P + 256) * sizeof(float) + (4 + 257) * sizeof(int);
    if (ws_size < need_bytes) return;

    k_gemm<0><<<dim3(128, 8), 256, 0, stream>>>(F, T, Kb, partials, nullptr, nullptr, flags);
    k_init<<<8, 128, 0, stream>>>(partials, ktu, vcom, err2, flags, bar);
    k_persist<<<PBLK, PTHR, 0, stream>>>(Kb, ratios, ktu, utmp, vcom, partials,
                                         err2, flags, bar);
    k_gemm<1><<<dim3(128, 8), 256, 0, stream>>>(F, T, out, nullptr, vcom, utmp, flags);
}

// Round 5
// 2128.450 us; speedup vs baseline: 3.0782x; 3.0782x over previous
//
#include <hip/hip_runtime.h>
#include <hip/hip_bf16.h>

typedef float   f32x4_t  __attribute__((ext_vector_type(4)));
typedef float   f32x2_t  __attribute__((ext_vector_type(2)));
typedef __bf16  bf16x8_t __attribute__((ext_vector_type(8)));
typedef int     i32x4_t  __attribute__((ext_vector_type(4)));

#define N_ROWS   16384
#define N_COLS   1000
#define N_COLS_P 1024
#define N_DIM    512
#define N_ITER   100
#define PBLK     256
#define PTHR     512
#define RED0     64        /* reducer blocks: [RED0, RED0+64) */

// ---- relaxed agent-scope (sc1) accessors: coherent, no buffer_inv/wbl2 ----
__device__ __forceinline__ float ldf_sc1(const float* p) {
    return __hip_atomic_load(p, __ATOMIC_RELAXED, __HIP_MEMORY_SCOPE_AGENT);
}
__device__ __forceinline__ void stf_sc1(float* p, float v) {
    __hip_atomic_store(p, v, __ATOMIC_RELAXED, __HIP_MEMORY_SCOPE_AGENT);
}
__device__ __forceinline__ int ldi_sc1(const int* p) {
    return __hip_atomic_load(p, __ATOMIC_RELAXED, __HIP_MEMORY_SCOPE_AGENT);
}
__device__ __forceinline__ void sti_sc1(int* p, int v) {
    __hip_atomic_store(p, v, __ATOMIC_RELAXED, __HIP_MEMORY_SCOPE_AGENT);
}
__device__ __forceinline__ void st2_sc1(float* p, float a, float b) {
    const unsigned long long u =
        ((unsigned long long)__builtin_bit_cast(unsigned, b) << 32) |
        __builtin_bit_cast(unsigned, a);
    __hip_atomic_store((unsigned long long*)p, u, __ATOMIC_RELAXED,
                       __HIP_MEMORY_SCOPE_AGENT);
}

__device__ __forceinline__ unsigned short f2bf(float f) {
    unsigned int u = __builtin_bit_cast(unsigned int, f);
    u += 0x7FFFu + ((u >> 16) & 1u);            // RNE round to bf16
    return (unsigned short)(u >> 16);
}

// Grid barrier, relaxed-only. Release = vmcnt drain at __syncthreads entry;
// acquire = all cross-block data uses sc1 accessors (bypasses stale L2).
__device__ __forceinline__ void gridbar(int* bar, int g) {
    __syncthreads();                 // drains vmcnt: prior sc1 stores visible
    if (blockIdx.x == 0) {
        if (threadIdx.x < 64) {
            const int l = threadIdx.x;
            for (;;) {
                int ok = 1;
#pragma unroll
                for (int h = 0; h < 4; ++h) {
                    const int slot = (h << 6) + l;
                    if (slot) ok &= (ldi_sc1(bar + slot) >= g);
                }
                if (__all(ok)) break;
            }
            if (l == 0) sti_sc1(bar + 256, g);
        }
    } else {
        if (threadIdx.x == 0) {
            sti_sc1(bar + (int)blockIdx.x, g);
            while (ldi_sc1(bar + 256) < g) __builtin_amdgcn_s_sleep(2);
        }
    }
    __syncthreads();
}

// ---------------------------------------------------------------------------
// GEMM pass: dot = F @ T^T ; K = exp(-2*s/(1-s)), s=2*dot.
// MODE 0: K as bf16 (stride 1024, zero-padded) into d_out + column partials.
// MODE 1: final plan out[i][j] = u[i]*K[i][j]*v[j] (f32, stride 1000).
// ---------------------------------------------------------------------------
template <int MODE>
__launch_bounds__(256)
__global__ void k_gemm(const float* __restrict__ F, const float* __restrict__ T,
                       void* __restrict__ Kout, float* __restrict__ cpart,
                       const float* __restrict__ v_com, const float* __restrict__ u_both,
                       const int* __restrict__ flags)
{
    __shared__ unsigned short lA[128 * 72];
    __shared__ unsigned short lB[128 * 72];
    __shared__ float cs_lds[4 * 64];

    const int bm = blockIdx.x;
    const int bn = blockIdx.y;
    const int m0 = bm << 7;
    const int n0 = bn << 7;
    const int t  = threadIdx.x;
    const int lane = t & 63;
    const int wid  = t >> 6;
    const int wr = wid >> 1;
    const int wc = wid & 1;

    f32x4_t acc[4][4];
#pragma unroll
    for (int a = 0; a < 4; ++a)
#pragma unroll
        for (int b = 0; b < 4; ++b)
            acc[a][b] = (f32x4_t){0.f, 0.f, 0.f, 0.f};

    const int srow = t >> 4;
    const int scol = (t & 15) << 2;

    for (int kt = 0; kt < N_DIM; kt += 64) {
#pragma unroll
        for (int r = 0; r < 8; ++r) {
            const int rr = srow + (r << 4);
            const float4 av = *(const float4*)(F + (size_t)(m0 + rr) * N_DIM + kt + scol);
            ushort4 a4; a4.x = f2bf(av.x); a4.y = f2bf(av.y); a4.z = f2bf(av.z); a4.w = f2bf(av.w);
            *(ushort4*)(&lA[rr * 72 + scol]) = a4;
            const int gn = n0 + rr;
            float4 bv = make_float4(0.f, 0.f, 0.f, 0.f);
            if (gn < N_COLS) bv = *(const float4*)(T + (size_t)gn * N_DIM + kt + scol);
            ushort4 b4; b4.x = f2bf(bv.x); b4.y = f2bf(bv.y); b4.z = f2bf(bv.z); b4.w = f2bf(bv.w);
            *(ushort4*)(&lB[rr * 72 + scol]) = b4;
        }
        __syncthreads();
#pragma unroll
        for (int ks = 0; ks < 2; ++ks) {
            bf16x8_t afr[4], bfr[4];
#pragma unroll
            for (int mf = 0; mf < 4; ++mf) {
                const int r = (wr << 6) + (mf << 4) + (lane & 15);
                const int off = r * 72 + (ks << 5) + ((lane >> 4) << 3);
                afr[mf] = __builtin_bit_cast(bf16x8_t, *(const i32x4_t*)(&lA[off]));
            }
#pragma unroll
            for (int nf = 0; nf < 4; ++nf) {
                const int r = (wc << 6) + (nf << 4) + (lane & 15);
                const int off = r * 72 + (ks << 5) + ((lane >> 4) << 3);
                bfr[nf] = __builtin_bit_cast(bf16x8_t, *(const i32x4_t*)(&lB[off]));
            }
#pragma unroll
            for (int mf = 0; mf < 4; ++mf)
#pragma unroll
                for (int nf = 0; nf < 4; ++nf)
                    acc[mf][nf] = __builtin_amdgcn_mfma_f32_16x16x32_bf16(
                        afr[mf], bfr[nf], acc[mf][nf], 0, 0, 0);
        }
        __syncthreads();
    }

    int usel = 2;
    if (MODE == 1) usel = flags[1];
    float csum[4] = {0.f, 0.f, 0.f, 0.f};
#pragma unroll
    for (int mf = 0; mf < 4; ++mf) {
#pragma unroll
        for (int nf = 0; nf < 4; ++nf) {
#pragma unroll
            for (int j = 0; j < 4; ++j) {
                const float d = acc[mf][nf][j];
                const float s = 2.f * d;
                const float M = s / (1.f - s);
                const float kv = __expf(-2.f * M);
                const int grow = m0 + (wr << 6) + (mf << 4) + ((lane >> 4) << 2) + j;
                const int gcol = n0 + (wc << 6) + (nf << 4) + (lane & 15);
                if (MODE == 0) {
                    ((unsigned short*)Kout)[(size_t)grow * N_COLS_P + gcol] =
                        (gcol < N_COLS) ? f2bf(kv) : (unsigned short)0;
                    csum[nf] += kv;
                } else {
                    if (gcol < N_COLS) {
                        const float u = (usel == 2) ? (1.f / 16384.f)
                                                    : u_both[(size_t)usel * N_ROWS + grow];
                        ((float*)Kout)[(size_t)grow * N_COLS + gcol] = u * kv * v_com[gcol];
                    }
                }
            }
        }
    }
    if (MODE == 0) {
#pragma unroll
        for (int nf = 0; nf < 4; ++nf) {
            csum[nf] += __shfl_xor(csum[nf], 16);
            csum[nf] += __shfl_xor(csum[nf], 32);
        }
        if (lane < 16) {
#pragma unroll
            for (int nf = 0; nf < 4; ++nf)
                cs_lds[wid * 64 + (nf << 4) + lane] = csum[nf];
        }
        __syncthreads();
        if (t < 128) {
            const int cw = t >> 6;
            const int c6 = t & 63;
            cpart[(size_t)bm * N_COLS_P + n0 + t] =
                cs_lds[cw * 64 + c6] + cs_lds[(cw + 2) * 64 + c6];
        }
    }
}

// ---------------------------------------------------------------------------
// init: KtU0 = colsum(K)/16384, v_com = 1/1000, pads = 1.0, flags/bar reset.
// flags: [0]=unused [1]=u_sel (2=uniform u0) [2]=bad [3]=unused
// ---------------------------------------------------------------------------
__launch_bounds__(128)
__global__ void k_init(const float* __restrict__ cpart, float* __restrict__ ktu0,
                       float* __restrict__ vcom, float* __restrict__ err2,
                       int* __restrict__ flags, int* __restrict__ bar)
{
    const int j = blockIdx.x * 128 + threadIdx.x;   // 0..1023
    if (j < N_COLS) {
        float s = 0.f;
        for (int p = 0; p < 128; ++p) s += cpart[(size_t)p * N_COLS_P + j];
        ktu0[j] = s * (1.f / 16384.f);
        vcom[j] = 1.f / 1000.f;
    } else {
        ktu0[j] = 1.f;                 // pad: b=0 -> v=0 (finite)
        vcom[j] = 0.f;
    }
    if (j <= 256) bar[j] = 0;          // 256 slots + generation
    if (j < 64) err2[j] = 0.f;
    if (j == 0) { flags[0] = 0; flags[1] = 2; flags[2] = 0; flags[3] = 0; }
}

// ---------------------------------------------------------------------------
// Persistent Sinkhorn loop. 256 blocks x 512 thr. Lane owns column PAIRS
// {128q + 2*lane + e}; 8 rows/wave; packed bf16 K in 64 VGPRs.
// A) vnew -> dots -> u_new -> per-block col partials (sc1);  gridbar
// B) blocks [64,128) reduce 16 contiguous cols each (sc1);   gridbar
// C) uniform done/converged decision (every block, same data).
// ---------------------------------------------------------------------------
__launch_bounds__(PTHR, 2)
__global__ void k_persist(const unsigned short* __restrict__ Kb,
                          const float* __restrict__ ratios,
                          float* __restrict__ ktu,      // [2][1024]
                          float* __restrict__ utmp,     // [2][16384]
                          float* __restrict__ vcom,     // [1024]
                          float* __restrict__ partials, // [256][1024]
                          float* __restrict__ err2,     // [64]
                          int* __restrict__ flags,
                          int* __restrict__ bar)        // [257]
{
    __shared__ float vnew[N_COLS_P];
    __shared__ float wp[8][N_COLS_P];
    __shared__ float wred[8][16];
    __shared__ float errl[16];
    __shared__ int ibc[2];
    const int t = threadIdx.x, lane = t & 63, wid = t >> 6, b = blockIdx.x;
    const int row0 = (b << 6) + (wid << 3);
    const int rb = b - RED0;                   // reducer index, valid in [0,64)
    const bool isred = (rb >= 0 && rb < 64);

    // K preload: packed bf16 pairs, fully coalesced dword loads (plain/cached).
    unsigned kp[8][8];
#pragma unroll
    for (int r = 0; r < 8; ++r) {
        const unsigned* rp = (const unsigned*)(Kb + (size_t)(row0 + r) * N_COLS_P);
#pragma unroll
        for (int q = 0; q < 8; ++q) kp[r][q] = rp[(q << 6) + lane];
    }
    const float bj0 = (t < N_COLS) ? ratios[t] * 16384.f : 0.f;
    const float bj1 = (t + PTHR < N_COLS) ? ratios[t + PTHR] * 16384.f : 0.f;

    int bar_g = 0;
    int usel = 2;

    for (int ii = 0; ii < N_ITER; ++ii) {
        const int p = ii & 1;
        float* __restrict__ ktu_cur = ktu + p * N_COLS_P;
        float* __restrict__ ktu_nxt = ktu + (1 - p) * N_COLS_P;

        // ---- phase A ----
        int badl = 0;
        {
            const float v0 = bj0 / ldf_sc1(ktu_cur + t);
            const float v1 = bj1 / ldf_sc1(ktu_cur + t + PTHR);
            badl |= !isfinite(v0) | !isfinite(v1);
            vnew[t] = v0;
            vnew[t + PTHR] = v1;
        }
        __syncthreads();
        float vr[16];
#pragma unroll
        for (int q = 0; q < 8; ++q) {
            const f32x2_t vv = *(const f32x2_t*)&vnew[(q << 7) + (lane << 1)];
            vr[2*q] = vv[0]; vr[2*q+1] = vv[1];
        }
        float dots[8];
#pragma unroll
        for (int r = 0; r < 8; ++r) {
            float p0 = 0.f, p1 = 0.f, p2 = 0.f, p3 = 0.f;
#pragma unroll
            for (int q = 0; q < 8; ++q) {
                const unsigned u = kp[r][q];
                const float lo = __builtin_bit_cast(float, u << 16);
                const float hi = __builtin_bit_cast(float, u & 0xFFFF0000u);
                if (q & 1) { p2 = fmaf(lo, vr[2*q], p2); p3 = fmaf(hi, vr[2*q+1], p3); }
                else       { p0 = fmaf(lo, vr[2*q], p0); p1 = fmaf(hi, vr[2*q+1], p1); }
            }
            dots[r] = (p0 + p1) + (p2 + p3);
        }
#pragma unroll
        for (int s = 1; s <= 32; s <<= 1) {
#pragma unroll
            for (int r = 0; r < 8; ++r) dots[r] += __shfl_xor(dots[r], s);
        }
        float u8[8];
#pragma unroll
        for (int r = 0; r < 8; ++r) { u8[r] = 1.f / dots[r]; badl |= !isfinite(u8[r]); }
        if (lane == 0) {
            float* uo = utmp + (size_t)p * N_ROWS + row0;
#pragma unroll
            for (int r = 0; r < 8; ++r) uo[r] = u8[r];
        }
        if (__any(badl) && lane == 0)
            __hip_atomic_fetch_or(&flags[2], 1, __ATOMIC_RELAXED, __HIP_MEMORY_SCOPE_AGENT);

        float creg[16];
#pragma unroll
        for (int e = 0; e < 16; ++e) creg[e] = 0.f;
#pragma unroll
        for (int r = 0; r < 8; ++r) {
#pragma unroll
            for (int q = 0; q < 8; ++q) {
                const unsigned u = kp[r][q];
                const float lo = __builtin_bit_cast(float, u << 16);
                const float hi = __builtin_bit_cast(float, u & 0xFFFF0000u);
                creg[2*q]   = fmaf(lo, u8[r], creg[2*q]);
                creg[2*q+1] = fmaf(hi, u8[r], creg[2*q+1]);
            }
        }
#pragma unroll
        for (int q = 0; q < 8; ++q)
            *(f32x2_t*)&wp[wid][(q << 7) + (lane << 1)] = (f32x2_t){creg[2*q], creg[2*q+1]};
        __syncthreads();
        {
            const int j2 = t << 1;
            f32x2_t s2 = *(const f32x2_t*)&wp[0][j2];
#pragma unroll
            for (int w = 1; w < 8; ++w) {
                const f32x2_t x = *(const f32x2_t*)&wp[w][j2];
                s2[0] += x[0]; s2[1] += x[1];
            }
            st2_sc1(&partials[(size_t)b * N_COLS_P + j2], s2[0], s2[1]);
        }
        ++bar_g; gridbar(bar, bar_g);

        // ---- phase B (blocks [64,128)): coalesced sc1 reduce ----
        if (t == 0) ibc[0] = ldi_sc1(&flags[2]);
        __syncthreads();
        const int bad = ibc[0];
        float bsum = 0.f;
        if (!bad && isred) {
            const int col = (rb << 4) + (t & 15);
            const int rgrp = t >> 4;               // 0..31
#pragma unroll
            for (int k = 0; k < 8; ++k)
                bsum += ldf_sc1(&partials[(size_t)(rgrp + (k << 5)) * N_COLS_P + col]);
            bsum += __shfl_xor(bsum, 16);
            bsum += __shfl_xor(bsum, 32);
            if (lane < 16) wred[wid][lane] = bsum;
        }
        __syncthreads();
        if (!bad && isred && t < 16) {
            const int col = (rb << 4) + t;
            float s = 0.f;
#pragma unroll
            for (int w = 0; w < 8; ++w) s += wred[w][t];
            float errc = 0.f;
            if (col < N_COLS) {
                stf_sc1(&ktu_nxt[col], s);
                const float bj = ratios[col] * 16384.f;
                const float vn = bj / ldf_sc1(&ktu_cur[col]);
                const float d  = s * vn - bj;
                errc = d * d;
            } else {
                stf_sc1(&ktu_nxt[col], 1.f);
            }
            errl[t] = errc;
        }
        __syncthreads();
        if (!bad && isred && t == 0) {
            float e = 0.f;
#pragma unroll
            for (int i = 0; i < 16; ++i) e += errl[i];
            stf_sc1(&err2[rb], e);
        }
        ++bar_g; gridbar(bar, bar_g);

        // ---- phase C (uniform decision across blocks) ----
        if (bad) break;                  // revert: ktu/usel untouched this iter
        usel = p;                        // live commit
        if ((ii % 10) == 0) {
            float e = (t < 64) ? ldf_sc1(&err2[t]) : 0.f;
            if (t < 64) {
#pragma unroll
                for (int sh = 1; sh <= 32; sh <<= 1) e += __shfl_xor(e, sh);
            }
            if (t == 0) ibc[1] = (e < 1e-18f) ? 1 : 0;
            __syncthreads();
            const int conv = ibc[1];
            __syncthreads();
            if (conv) break;             // converged (after committing this iter)
        }
    }

    if (isred && t < 16 && usel != 2) {
        const int col = (rb << 4) + t;
        if (col < N_COLS)
            vcom[col] = (ratios[col] * 16384.f) /
                        ldf_sc1(&ktu[(size_t)usel * N_COLS_P + col]);
    }
    if (b == 0 && t == 0) flags[1] = usel;
}

extern "C" void kernel_launch(void* const* d_in, const int* in_sizes, int n_in,
                              void* d_out, int out_size, void* d_ws, size_t ws_size,
                              hipStream_t stream)
{
    const float* F      = (const float*)d_in[0];
    const float* T      = (const float*)d_in[1];
    const float* ratios = (const float*)d_in[2];
    float* out = (float*)d_out;
    unsigned short* Kb = (unsigned short*)d_out;   // bf16 K, stride 1024

    float* ws        = (float*)d_ws;
    float* partials  = ws;                                   // 256*1024
    float* ktu       = partials + (size_t)PBLK * N_COLS_P;   // 2*1024
    float* utmp      = ktu + 2 * N_COLS_P;                   // 2*16384
    float* vcom      = utmp + 2 * N_ROWS;                    // 1024
    float* err2      = vcom + N_COLS_P;                      // 64
    int*   flags     = (int*)(err2 + 64);                    // 4
    int*   bar       = flags + 4;                            // 257
    const size_t need_bytes = ((size_t)PBLK * N_COLS_P + 2 * N_COLS_P + 2 * N_ROWS +
                               N_COLS_P + 64) * sizeof(float) + (4 + 257) * sizeof(int);
    if (ws_size < need_bytes) return;

    k_gemm<0><<<dim3(128, 8), 256, 0, stream>>>(F, T, Kb, partials, nullptr, nullptr, flags);
    k_init<<<8, 128, 0, stream>>>(partials, ktu, vcom, err2, flags, bar);
    k_persist<<<PBLK, PTHR, 0, stream>>>(Kb, ratios, ktu, utmp, vcom, partials,
                                         err2, flags, bar);
    k_gemm<1><<<dim3(128, 8), 256, 0, stream>>>(F, T, out, nullptr, vcom, utmp, flags);
}